// Round 8
// baseline (1228.984 us; speedup 1.0000x reference)
//
#include <hip/hip_runtime.h>
#include <hip/hip_bf16.h>

#define BB 64
#define SS 2048
#define II 64
#define HH 128
#define CH 64   // timestep chunk of wx staged in LDS
#define BPB 2   // batch elements per block (one group of 4 waves each)

typedef _Float16 half8 __attribute__((ext_vector_type(8)));
typedef float f32x4 __attribute__((ext_vector_type(4)));

#define LOG2E 1.44269504088896340736f

__device__ __forceinline__ float sigm(float x) { return 1.0f / (1.0f + __expf(-x)); }

// wx0[b,s,j] = sum_i x[b,s,i] * w0[i,j]   (layout [b][s][j])
__global__ __launch_bounds__(256, 4)
void wx0_kernel(const float* __restrict__ x, const float* __restrict__ w0,
                float* __restrict__ wx0) {
  __shared__ float xs[32][64];
  const int tid = threadIdx.x;
  const int j = tid & (HH - 1);
  const int rh = tid >> 7;
  const long row0 = (long)blockIdx.x * 32;

  float w0c[II];
#pragma unroll
  for (int i = 0; i < II; ++i) w0c[i] = w0[i * HH + j];

  const float4* xg = (const float4*)(x + row0 * II);
  float4* xsv = (float4*)&xs[0][0];
  xsv[tid] = xg[tid];
  xsv[tid + 256] = xg[tid + 256];
  __syncthreads();

#pragma unroll
  for (int rp = 0; rp < 16; ++rp) {
    int r = rp * 2 + rh;
    float acc = 0.f;
#pragma unroll
    for (int i = 0; i < II; i += 4) {
      float4 xv = *(const float4*)&xs[r][i];
      acc += w0c[i] * xv.x + w0c[i + 1] * xv.y + w0c[i + 2] * xv.z +
             w0c[i + 3] * xv.w;
    }
    wx0[(row0 + r) * HH + j] = acc;
  }
}

// Fused 2-layer scan. BPB=2 batch elements per block (4 waves each, 512 thr):
// each SIMD hosts 2 independent per-batch instruction streams, hiding the
// serial step latency that bounded the 1-wave/SIMD version (R7 post-mortem).
// Per batch group (256 threads), layer-skewed recurrence:
//   iter t: h0[t+1] = G0(h0[t], wx[t+1]);  h1[t] = G1(h1[t-1], h0@w1 + h1@u1)
// MFMA 16x16x32_f16, row-replicated A (acc[0] valid on every lane),
// K chained through the MFMA C operand. Gate duty: parity=g&1, colsel=g>>1.
__global__ __launch_bounds__(512, 1)
void scan_kernel(const float* __restrict__ wx0,
                 const float* __restrict__ u0, const float* __restrict__ bg0,
                 const float* __restrict__ bu0, const float* __restrict__ zeta0,
                 const float* __restrict__ nu0, const float* __restrict__ lambd0,
                 const float* __restrict__ gamma0,
                 const float* __restrict__ w1, const float* __restrict__ u1,
                 const float* __restrict__ bg1, const float* __restrict__ bu1,
                 const float* __restrict__ zeta1, const float* __restrict__ nu1,
                 const float* __restrict__ lambd1, const float* __restrict__ gamma1,
                 float* __restrict__ out1, float* __restrict__ hn) {
  const int tid = threadIdx.x;
  const int grp = tid >> 8;            // batch slot within block
  const int tl = tid & 255;            // thread id within group
  const int b = blockIdx.x * BPB + grp;
  const int w = tl >> 6;               // wave within group (0..3)
  const int l = tid & 63;
  const int g = l >> 4;
  const int n = l & 15;
  const int c0 = 32 * w + n;
  const int c1 = c0 + 16;
  const int parity = g & 1;    // 0: layer0 duty, 1: layer1 duty
  const int colsel = g >> 1;   // 0: c0, 1: c1

  // ---- weight B-fragments (f16): elem i -> k = 32kt + (i<4 ? 4g+i : 16+4g+i-4)
  half8 wf[3][2][4];
#pragma unroll
  for (int mt = 0; mt < 3; ++mt) {
    const float* W = (mt == 0) ? u0 : (mt == 1) ? w1 : u1;
#pragma unroll
    for (int nt = 0; nt < 2; ++nt) {
      const int col = 32 * w + 16 * nt + n;
#pragma unroll
      for (int kt = 0; kt < 4; ++kt) {
        half8 f;
#pragma unroll
        for (int i = 0; i < 8; ++i) {
          int k = 32 * kt + (i < 4 ? 4 * g + i : 16 + 4 * g + (i - 4));
          f[i] = (_Float16)W[k * HH + col];
        }
        wf[mt][nt][kt] = f;
      }
    }
  }

  // ---- per-parity gate constants
  const float szg = parity ? sigm(zeta1[0]) : sigm(zeta0[0]);
  const float sng = parity ? sigm(nu1[0]) : sigm(nu0[0]);
  const float gcraw = parity ? gamma1[0] : gamma0[0];
  const float gcg = fminf(fmaxf(gcraw, 0.f), 1.f);
  const float kcg = (1.f - gcg) * (parity ? lambd1[0] : lambd0[0]);
  const float ebg_0 = -LOG2E * (parity ? bg1[c0] : bg0[c0]);
  const float ebg_1 = -LOG2E * (parity ? bg1[c1] : bg0[c1]);
  const float ebu_0 = -2.f * LOG2E * (parity ? bu1[c0] : bu0[c0]);
  const float ebu_1 = -2.f * LOG2E * (parity ? bu1[c1] : bu0[c1]);

  auto gate = [](float pre, float hp, float eg, float eu, float sz, float sn,
                 float gc, float kc) -> float {
    float p  = __builtin_amdgcn_exp2f(__builtin_fmaf(pre, -LOG2E, eg));
    float qq = __builtin_amdgcn_exp2f(__builtin_fmaf(pre, -2.f * LOG2E, eu));
    float opp = 1.f + p, opq = 1.f + qq, omq = 1.f - qq;
    float t1 = __builtin_fmaf(sn, opp, sz * p);
    float num = __builtin_fmaf(hp, opq, t1 * omq);
    float hnew = num * __builtin_amdgcn_rcpf(opp * opq);
    return __builtin_fmaf(gc, hnew, kc);
  };

  // fragment-order packed h per batch slot: [grp][buf][layer][160 halves]
  __shared__ __align__(16) _Float16 Hpk[BPB][2][2][160];
  __shared__ __align__(16) float wxb[BPB][CH * HH];  // 32 KB each

  const float* wxg = wx0 + (size_t)b * SS * HH;
  float* outg = out1 + (size_t)b * SS * HH;

  const int widx = (w * 4 + (n >> 2)) * 8 + (n & 3) + (colsel << 2);
  const int rbase = 8 * g;  // slot offset per group (halves): slot kt*4+g

  // ---- prologue: stage wx rows 1..64; h0[0] = G0(0, wx[0]); h1[-1]=0
  {
    const float4* src = (const float4*)(wxg + HH);
    float4* dst = (float4*)&wxb[grp][0];
#pragma unroll
    for (int i = 0; i < 8; ++i) dst[i * 256 + tl] = src[i * 256 + tl];
  }
  float hp0, hp1;  // previous h of this lane's duty layer, cols c0/c1
  {
    const float sz0 = sigm(zeta0[0]), sn0 = sigm(nu0[0]);
    const float gc0 = fminf(fmaxf(gamma0[0], 0.f), 1.f);
    const float kc0 = (1.f - gc0) * lambd0[0];
    float h00 = gate(wxg[c0], 0.f, -LOG2E * bg0[c0], -2.f * LOG2E * bu0[c0],
                     sz0, sn0, gc0, kc0);
    float h01 = gate(wxg[c1], 0.f, -LOG2E * bg0[c1], -2.f * LOG2E * bu0[c1],
                     sz0, sn0, gc0, kc0);
    hp0 = parity ? 0.f : h00;
    hp1 = parity ? 0.f : h01;
    float wv = parity ? 0.f : (colsel ? h01 : h00);
    Hpk[grp][0][parity][widx] = (_Float16)wv;
  }
  asm volatile("s_waitcnt lgkmcnt(0)" ::: "memory");
  __builtin_amdgcn_s_barrier();

  const f32x4 zero = {0.f, 0.f, 0.f, 0.f};

  for (int t = 0; t < SS; ++t) {
    const int rd = t & 1, wr = rd ^ 1;
    const int q = t & (CH - 1);

    // ---- broadcast A-fragments (all lanes; rows replicated)
    half8 a0[4], a1[4];
#pragma unroll
    for (int kt = 0; kt < 4; ++kt) {
      a0[kt] = __builtin_bit_cast(half8,
                 *(const uint4*)&Hpk[grp][rd][0][kt * 32 + rbase]);
      a1[kt] = __builtin_bit_cast(half8,
                 *(const uint4*)&Hpk[grp][rd][1][kt * 32 + rbase]);
    }
    float wxv0 = wxb[grp][q * HH + c0];
    float wxv1 = wxb[grp][q * HH + c1];

    // ---- 6 matvec accumulators, K chained through the MFMA C operand
    f32x4 accA0, accA1, accB0, accB1, accC0, accC1;
#pragma unroll
    for (int kt = 0; kt < 4; ++kt) {
      accA0 = __builtin_amdgcn_mfma_f32_16x16x32_f16(a0[kt], wf[0][0][kt], kt ? accA0 : zero, 0, 0, 0);
      accA1 = __builtin_amdgcn_mfma_f32_16x16x32_f16(a0[kt], wf[0][1][kt], kt ? accA1 : zero, 0, 0, 0);
      accB0 = __builtin_amdgcn_mfma_f32_16x16x32_f16(a0[kt], wf[1][0][kt], kt ? accB0 : zero, 0, 0, 0);
      accB1 = __builtin_amdgcn_mfma_f32_16x16x32_f16(a0[kt], wf[1][1][kt], kt ? accB1 : zero, 0, 0, 0);
      accC0 = __builtin_amdgcn_mfma_f32_16x16x32_f16(a1[kt], wf[2][0][kt], kt ? accC0 : zero, 0, 0, 0);
      accC1 = __builtin_amdgcn_mfma_f32_16x16x32_f16(a1[kt], wf[2][1][kt], kt ? accC1 : zero, 0, 0, 0);
    }
    float sumA0 = accA0[0], sumA1 = accA1[0];
    float sumB0 = accB0[0], sumB1 = accB1[0];
    float sumC0 = accC0[0], sumC1 = accC1[0];

    // ---- gates (parity-split duty)
    float pre_0 = parity ? (sumB0 + sumC0) : (sumA0 + wxv0);
    float pre_1 = parity ? (sumB1 + sumC1) : (sumA1 + wxv1);
    float hc0 = gate(pre_0, hp0, ebg_0, ebu_0, szg, sng, gcg, kcg);
    float hc1 = gate(pre_1, hp1, ebg_1, ebu_1, szg, sng, gcg, kcg);
    hp0 = hc0;
    hp1 = hc1;

    // ---- publish h (1 b16/lane, fragment order) + global stores
    float wval = colsel ? hc1 : hc0;
    Hpk[grp][wr][parity][widx] = (_Float16)wval;
    if (parity) {  // layer1 output
      outg[(size_t)t * HH + (colsel ? c1 : c0)] = wval;
      if (t == SS - 1) hn[BB * HH + b * HH + (colsel ? c1 : c0)] = wval;
    } else {
      if (t == SS - 2) hn[b * HH + (colsel ? c1 : c0)] = wval;  // h0[SS-1]
    }

    asm volatile("s_waitcnt lgkmcnt(0)" ::: "memory");
    __builtin_amdgcn_s_barrier();

    // ---- chunk boundary: restage wx rows t+2 .. t+65 (clamped)
    if (q == CH - 1 && t + 1 < SS) {
      float4* wdst = (float4*)&wxb[grp][0];
#pragma unroll
      for (int i = 0; i < 8; ++i) {
        int flat4 = i * 256 + tl;
        int row = t + 2 + (flat4 >> 5);
        row = row < SS ? row : SS - 1;
        int col4 = flat4 & 31;
        wdst[flat4] = *(const float4*)(wxg + (size_t)row * HH + col4 * 4);
      }
      asm volatile("s_waitcnt lgkmcnt(0)" ::: "memory");
      __builtin_amdgcn_s_barrier();
    }
  }
}

extern "C" void kernel_launch(void* const* d_in, const int* in_sizes, int n_in,
                              void* d_out, int out_size, void* d_ws, size_t ws_size,
                              hipStream_t stream) {
  const float* x      = (const float*)d_in[0];
  const float* w0     = (const float*)d_in[1];
  const float* u0     = (const float*)d_in[2];
  const float* bg0    = (const float*)d_in[3];
  const float* bu0    = (const float*)d_in[4];
  const float* zeta0  = (const float*)d_in[5];
  const float* nu0    = (const float*)d_in[6];
  const float* lambd0 = (const float*)d_in[7];
  const float* gamma0 = (const float*)d_in[8];
  const float* w1     = (const float*)d_in[9];
  const float* u1     = (const float*)d_in[10];
  const float* bg1    = (const float*)d_in[11];
  const float* bu1    = (const float*)d_in[12];
  const float* zeta1  = (const float*)d_in[13];
  const float* nu1    = (const float*)d_in[14];
  const float* lambd1 = (const float*)d_in[15];
  const float* gamma1 = (const float*)d_in[16];

  float* out = (float*)d_out;                     // out1: [B,S,H]
  float* hn  = out + (size_t)BB * SS * HH;        // h_n:  [2,B,H]
  float* wx0 = (float*)d_ws;                      // scratch: [B,S,H] fp32 (64 MB)

  wx0_kernel<<<(BB * SS) / 32, 256, 0, stream>>>(x, w0, wx0);
  scan_kernel<<<BB / BPB, 256 * BPB, 0, stream>>>(wx0, u0, bg0, bu0, zeta0, nu0,
                                                  lambd0, gamma0, w1, u1, bg1,
                                                  bu1, zeta1, nu1, lambd1,
                                                  gamma1, out, hn);
}

// Round 9
// 933.419 us; speedup vs baseline: 1.3166x; 1.3166x over previous
//
#include <hip/hip_runtime.h>
#include <hip/hip_bf16.h>

#define BB 64
#define SS 2048
#define II 64
#define HH 128
#define CH 64   // timestep chunk of wx staged in LDS

typedef _Float16 half8 __attribute__((ext_vector_type(8)));
typedef float f32x4 __attribute__((ext_vector_type(4)));

#define LOG2E 1.44269504088896340736f

__device__ __forceinline__ float sigm(float x) { return 1.0f / (1.0f + __expf(-x)); }

// wx0[b,s,j] = sum_i x[b,s,i] * w0[i,j]   (layout [b][s][j])
__global__ __launch_bounds__(256, 4)
void wx0_kernel(const float* __restrict__ x, const float* __restrict__ w0,
                float* __restrict__ wx0) {
  __shared__ float xs[32][64];
  const int tid = threadIdx.x;
  const int j = tid & (HH - 1);
  const int rh = tid >> 7;
  const long row0 = (long)blockIdx.x * 32;

  float w0c[II];
#pragma unroll
  for (int i = 0; i < II; ++i) w0c[i] = w0[i * HH + j];

  const float4* xg = (const float4*)(x + row0 * II);
  float4* xsv = (float4*)&xs[0][0];
  xsv[tid] = xg[tid];
  xsv[tid + 256] = xg[tid + 256];
  __syncthreads();

#pragma unroll
  for (int rp = 0; rp < 16; ++rp) {
    int r = rp * 2 + rh;
    float acc = 0.f;
#pragma unroll
    for (int i = 0; i < II; i += 4) {
      float4 xv = *(const float4*)&xs[r][i];
      acc += w0c[i] * xv.x + w0c[i + 1] * xv.y + w0c[i + 2] * xv.z +
             w0c[i + 3] * xv.w;
    }
    wx0[(row0 + r) * HH + j] = acc;
  }
}

// Fused 2-layer scan, one block per batch, 8 waves (512 thr), layer-skewed:
//   iter t: h0[t+1] = G0(h0[t], wx[t+1]);  h1[t] = G1(h1[t-1], h0@w1 + h1@u1)
// Work split: wave w owns column-tile w (cols 16w..16w+15) for ALL THREE
// matvecs: A-tile (h0@u0), B-tile (h0@w1), C-tile (h1@u1) = 12 MFMA/wave.
// 2 waves/SIMD -> per-SIMD MFMA pipe = 24 x ~16cyc = 384 (the floor), with
// two independent streams hiding each other's latencies (R8 lesson).
// Row-replicated A (acc[0] valid on every lane) -> gates computed 4x
// redundantly across g; writer lanes: g0 -> h0 LDS, g1 -> h1 LDS,
// g2 -> out1 global, g3 -> hn global. One barrier per step.
__global__ __launch_bounds__(512, 1)
void scan_kernel(const float* __restrict__ wx0,
                 const float* __restrict__ u0, const float* __restrict__ bg0,
                 const float* __restrict__ bu0, const float* __restrict__ zeta0,
                 const float* __restrict__ nu0, const float* __restrict__ lambd0,
                 const float* __restrict__ gamma0,
                 const float* __restrict__ w1, const float* __restrict__ u1,
                 const float* __restrict__ bg1, const float* __restrict__ bu1,
                 const float* __restrict__ zeta1, const float* __restrict__ nu1,
                 const float* __restrict__ lambd1, const float* __restrict__ gamma1,
                 float* __restrict__ out1, float* __restrict__ hn) {
  const int b = blockIdx.x;
  const int tid = threadIdx.x;
  const int w = tid >> 6;              // wave = column tile (0..7)
  const int l = tid & 63;
  const int g = l >> 4;
  const int n = l & 15;
  const int c = 16 * w + n;            // this lane's duty column

  // ---- weight B-fragments (f16) for tile w: elem i -> k = 32kt + kmap(g,i)
  half8 wfA[4], wfB[4], wfC[4];
#pragma unroll
  for (int kt = 0; kt < 4; ++kt) {
    half8 fa, fb, fc;
#pragma unroll
    for (int i = 0; i < 8; ++i) {
      int k = 32 * kt + (i < 4 ? 4 * g + i : 16 + 4 * g + (i - 4));
      fa[i] = (_Float16)u0[k * HH + c];
      fb[i] = (_Float16)w1[k * HH + c];
      fc[i] = (_Float16)u1[k * HH + c];
    }
    wfA[kt] = fa; wfB[kt] = fb; wfC[kt] = fc;
  }

  // ---- gate constants, both layers (every lane gates col c for L0 and L1)
  const float sz0 = sigm(zeta0[0]), sn0 = sigm(nu0[0]);
  const float gc0 = fminf(fmaxf(gamma0[0], 0.f), 1.f);
  const float kc0 = (1.f - gc0) * lambd0[0];
  const float sz1 = sigm(zeta1[0]), sn1 = sigm(nu1[0]);
  const float gc1 = fminf(fmaxf(gamma1[0], 0.f), 1.f);
  const float kc1 = (1.f - gc1) * lambd1[0];
  const float ebg0 = -LOG2E * bg0[c];
  const float ebu0 = -2.f * LOG2E * bu0[c];
  const float ebg1 = -LOG2E * bg1[c];
  const float ebu1 = -2.f * LOG2E * bu1[c];

  auto gate = [](float pre, float hp, float eg, float eu, float sz, float sn,
                 float gc, float kc) -> float {
    float p  = __builtin_amdgcn_exp2f(__builtin_fmaf(pre, -LOG2E, eg));
    float qq = __builtin_amdgcn_exp2f(__builtin_fmaf(pre, -2.f * LOG2E, eu));
    float opp = 1.f + p, opq = 1.f + qq, omq = 1.f - qq;
    float t1 = __builtin_fmaf(sn, opp, sz * p);
    float num = __builtin_fmaf(hp, opq, t1 * omq);
    float hnew = num * __builtin_amdgcn_rcpf(opp * opq);
    return __builtin_fmaf(gc, hnew, kc);
  };

  // fragment-order packed h: [buf][layer][160 halves]
  __shared__ __align__(16) _Float16 Hpk[2][2][160];
  __shared__ __align__(16) float wxb[CH * HH];  // 32 KB

  const float* wxg = wx0 + (size_t)b * SS * HH;
  float* outg = out1 + (size_t)b * SS * HH;

  // widx(c): fragment-order slot for column c
  const int wkt = c >> 5;
  const int wr_ = c & 31;
  const int widx = (wkt * 4 + ((wr_ & 15) >> 2)) * 8 + ((wr_ >> 4) << 2) + (wr_ & 3);
  const int rbase = 8 * g;

  // ---- prologue: stage wx rows 1..64 (2048 float4 / 512 thr = 4 each)
  {
    const float4* src = (const float4*)(wxg + HH);
    float4* dst = (float4*)wxb;
#pragma unroll
    for (int i = 0; i < 4; ++i) dst[i * 512 + tid] = src[i * 512 + tid];
  }
  // h0[0] = G0(0, wx[0]); h1[-1] = 0
  float hp0, hp1 = 0.f;
  {
    float h00 = gate(wxg[c], 0.f, ebg0, ebu0, sz0, sn0, gc0, kc0);
    hp0 = h00;
    if (g == 0) Hpk[0][0][widx] = (_Float16)h00;
    if (g == 1) Hpk[0][1][widx] = (_Float16)0.f;
  }
  asm volatile("s_waitcnt lgkmcnt(0)" ::: "memory");
  __builtin_amdgcn_s_barrier();

  const f32x4 zero = {0.f, 0.f, 0.f, 0.f};

  for (int t = 0; t < SS; ++t) {
    const int rd = t & 1, wb = rd ^ 1;
    const int q = t & (CH - 1);

    // ---- broadcast A-fragments (all lanes; rows replicated)
    half8 a0[4], a1[4];
#pragma unroll
    for (int kt = 0; kt < 4; ++kt) {
      a0[kt] = __builtin_bit_cast(half8,
                 *(const uint4*)&Hpk[rd][0][kt * 32 + rbase]);
      a1[kt] = __builtin_bit_cast(half8,
                 *(const uint4*)&Hpk[rd][1][kt * 32 + rbase]);
    }
    float wxv = wxb[q * HH + c];

    // ---- 3 matvec chains for tile w, K chained through the C operand
    f32x4 accA, accB, accC;
#pragma unroll
    for (int kt = 0; kt < 4; ++kt) {
      accA = __builtin_amdgcn_mfma_f32_16x16x32_f16(a0[kt], wfA[kt], kt ? accA : zero, 0, 0, 0);
      accB = __builtin_amdgcn_mfma_f32_16x16x32_f16(a0[kt], wfB[kt], kt ? accB : zero, 0, 0, 0);
      accC = __builtin_amdgcn_mfma_f32_16x16x32_f16(a1[kt], wfC[kt], kt ? accC : zero, 0, 0, 0);
    }

    // ---- gates (redundant across g; each lane does both layers for col c)
    float pre0 = accA[0] + wxv;
    float hc0 = gate(pre0, hp0, ebg0, ebu0, sz0, sn0, gc0, kc0);
    hp0 = hc0;
    if (g == 0) Hpk[wb][0][widx] = (_Float16)hc0;   // can issue before accC done

    float pre1 = accB[0] + accC[0];
    float hc1 = gate(pre1, hp1, ebg1, ebu1, sz1, sn1, gc1, kc1);
    hp1 = hc1;
    if (g == 1) Hpk[wb][1][widx] = (_Float16)hc1;
    if (g == 2) outg[(size_t)t * HH + c] = hc1;
    if (g == 3) {
      if (t == SS - 2) hn[b * HH + c] = hc0;                 // h0[SS-1]
      if (t == SS - 1) hn[BB * HH + b * HH + c] = hc1;       // h1[SS-1]
    }

    asm volatile("s_waitcnt lgkmcnt(0)" ::: "memory");
    __builtin_amdgcn_s_barrier();

    // ---- chunk boundary: restage wx rows t+2 .. t+65 (clamped)
    if (q == CH - 1 && t + 1 < SS) {
      float4* wdst = (float4*)wxb;
#pragma unroll
      for (int i = 0; i < 4; ++i) {
        int flat4 = i * 512 + tid;
        int row = t + 2 + (flat4 >> 5);
        row = row < SS ? row : SS - 1;
        int col4 = flat4 & 31;
        wdst[flat4] = *(const float4*)(wxg + (size_t)row * HH + col4 * 4);
      }
      asm volatile("s_waitcnt lgkmcnt(0)" ::: "memory");
      __builtin_amdgcn_s_barrier();
    }
  }
}

extern "C" void kernel_launch(void* const* d_in, const int* in_sizes, int n_in,
                              void* d_out, int out_size, void* d_ws, size_t ws_size,
                              hipStream_t stream) {
  const float* x      = (const float*)d_in[0];
  const float* w0     = (const float*)d_in[1];
  const float* u0     = (const float*)d_in[2];
  const float* bg0    = (const float*)d_in[3];
  const float* bu0    = (const float*)d_in[4];
  const float* zeta0  = (const float*)d_in[5];
  const float* nu0    = (const float*)d_in[6];
  const float* lambd0 = (const float*)d_in[7];
  const float* gamma0 = (const float*)d_in[8];
  const float* w1     = (const float*)d_in[9];
  const float* u1     = (const float*)d_in[10];
  const float* bg1    = (const float*)d_in[11];
  const float* bu1    = (const float*)d_in[12];
  const float* zeta1  = (const float*)d_in[13];
  const float* nu1    = (const float*)d_in[14];
  const float* lambd1 = (const float*)d_in[15];
  const float* gamma1 = (const float*)d_in[16];

  float* out = (float*)d_out;                     // out1: [B,S,H]
  float* hn  = out + (size_t)BB * SS * HH;        // h_n:  [2,B,H]
  float* wx0 = (float*)d_ws;                      // scratch: [B,S,H] fp32 (64 MB)

  wx0_kernel<<<(BB * SS) / 32, 256, 0, stream>>>(x, w0, wx0);
  scan_kernel<<<BB, 512, 0, stream>>>(wx0, u0, bg0, bu0, zeta0, nu0, lambd0,
                                      gamma0, w1, u1, bg1, bu1, zeta1, nu1,
                                      lambd1, gamma1, out, hn);
}

// Round 11
// 887.359 us; speedup vs baseline: 1.3850x; 1.0519x over previous
//
#include <hip/hip_runtime.h>
#include <hip/hip_bf16.h>

#define BB 64
#define SS 2048
#define II 64
#define HH 128
#define CH 64   // timestep chunk of wx staged in LDS

typedef _Float16 half8 __attribute__((ext_vector_type(8)));
typedef float f32x4 __attribute__((ext_vector_type(4)));

#define LOG2E 1.44269504088896340736f

__device__ __forceinline__ float sigm(float x) { return 1.0f / (1.0f + __expf(-x)); }

// wx0[b,s,j] = sum_i x[b,s,i] * w0[i,j]   (layout [b][s][j])
__global__ __launch_bounds__(256, 4)
void wx0_kernel(const float* __restrict__ x, const float* __restrict__ w0,
                float* __restrict__ wx0) {
  __shared__ float xs[32][64];
  const int tid = threadIdx.x;
  const int j = tid & (HH - 1);
  const int rh = tid >> 7;
  const long row0 = (long)blockIdx.x * 32;

  float w0c[II];
#pragma unroll
  for (int i = 0; i < II; ++i) w0c[i] = w0[i * HH + j];

  const float4* xg = (const float4*)(x + row0 * II);
  float4* xsv = (float4*)&xs[0][0];
  xsv[tid] = xg[tid];
  xsv[tid + 256] = xg[tid + 256];
  __syncthreads();

#pragma unroll
  for (int rp = 0; rp < 16; ++rp) {
    int r = rp * 2 + rh;
    float acc = 0.f;
#pragma unroll
    for (int i = 0; i < II; i += 4) {
      float4 xv = *(const float4*)&xs[r][i];
      acc += w0c[i] * xv.x + w0c[i + 1] * xv.y + w0c[i + 2] * xv.z +
             w0c[i + 3] * xv.w;
    }
    wx0[(row0 + r) * HH + j] = acc;
  }
}

// Fused 2-layer scan, one block per batch, 8 waves (512 thr), layer-skewed:
//   iter t: h0[t+1] = G0(h0[t], wx[t+1]);  h1[t] = G1(h1[t-1], h0@w1 + h1@u1)
// Wave w owns column-tile w (cols 16w..16w+15) for all three matvecs
// (12 MFMA/wave, 2 waves/SIMD). A-fragments are EXEC-MASKED to lanes n==0:
// only A-row 0 is real, so ONLY D-row 0 is valid, and D-row 0 lives on
// g==0 lanes reg 0 (R10 lesson: g1..g3 read garbage there -> all writers
// are g==0 now). LDS read delivery: 4 KiB/step/CU vs R9's 64 KiB broadcast
// wall (~770 cyc of LDS pipe). Gates computed on all lanes (exec-width)
// but only g0 results are stored. One barrier per step.
__global__ __launch_bounds__(512, 1)
void scan_kernel(const float* __restrict__ wx0,
                 const float* __restrict__ u0, const float* __restrict__ bg0,
                 const float* __restrict__ bu0, const float* __restrict__ zeta0,
                 const float* __restrict__ nu0, const float* __restrict__ lambd0,
                 const float* __restrict__ gamma0,
                 const float* __restrict__ w1, const float* __restrict__ u1,
                 const float* __restrict__ bg1, const float* __restrict__ bu1,
                 const float* __restrict__ zeta1, const float* __restrict__ nu1,
                 const float* __restrict__ lambd1, const float* __restrict__ gamma1,
                 float* __restrict__ out1, float* __restrict__ hn) {
  const int b = blockIdx.x;
  const int tid = threadIdx.x;
  const int w = tid >> 6;              // wave = column tile (0..7)
  const int l = tid & 63;
  const int g = l >> 4;
  const int n = l & 15;
  const int c = 16 * w + n;            // this lane's duty column

  // ---- weight B-fragments (f16) for tile w: elem i -> k = 32kt + kmap(g,i)
  half8 wfA[4], wfB[4], wfC[4];
#pragma unroll
  for (int kt = 0; kt < 4; ++kt) {
    half8 fa, fb, fc;
#pragma unroll
    for (int i = 0; i < 8; ++i) {
      int k = 32 * kt + (i < 4 ? 4 * g + i : 16 + 4 * g + (i - 4));
      fa[i] = (_Float16)u0[k * HH + c];
      fb[i] = (_Float16)w1[k * HH + c];
      fc[i] = (_Float16)u1[k * HH + c];
    }
    wfA[kt] = fa; wfB[kt] = fb; wfC[kt] = fc;
  }

  // ---- gate constants, both layers (lane gates col c for L0 and L1)
  const float sz0 = sigm(zeta0[0]), sn0 = sigm(nu0[0]);
  const float gc0 = fminf(fmaxf(gamma0[0], 0.f), 1.f);
  const float kc0 = (1.f - gc0) * lambd0[0];
  const float sz1 = sigm(zeta1[0]), sn1 = sigm(nu1[0]);
  const float gc1 = fminf(fmaxf(gamma1[0], 0.f), 1.f);
  const float kc1 = (1.f - gc1) * lambd1[0];
  const float ebg0 = -LOG2E * bg0[c];
  const float ebu0 = -2.f * LOG2E * bu0[c];
  const float ebg1 = -LOG2E * bg1[c];
  const float ebu1 = -2.f * LOG2E * bu1[c];

  auto gate = [](float pre, float hp, float eg, float eu, float sz, float sn,
                 float gc, float kc) -> float {
    float p  = __builtin_amdgcn_exp2f(__builtin_fmaf(pre, -LOG2E, eg));
    float qq = __builtin_amdgcn_exp2f(__builtin_fmaf(pre, -2.f * LOG2E, eu));
    float opp = 1.f + p, opq = 1.f + qq, omq = 1.f - qq;
    float t1 = __builtin_fmaf(sn, opp, sz * p);
    float num = __builtin_fmaf(hp, opq, t1 * omq);
    float hnew = num * __builtin_amdgcn_rcpf(opp * opq);
    return __builtin_fmaf(gc, hnew, kc);
  };

  // fragment-order packed h: [buf][layer][160 halves]
  __shared__ __align__(16) _Float16 Hpk[2][2][160];
  __shared__ __align__(16) float wxb[CH * HH];  // 32 KB

  const float* wxg = wx0 + (size_t)b * SS * HH;
  float* outg = out1 + (size_t)b * SS * HH;

  // widx(c): fragment-order slot for column c (inverse of kmap)
  const int wkt = c >> 5;
  const int wr_ = c & 31;
  const int widx = (wkt * 4 + ((wr_ & 15) >> 2)) * 8 + ((wr_ >> 4) << 2) + (wr_ & 3);
  const int rbase = 8 * g;

  // ---- prologue: stage wx rows 1..64 (2048 float4 / 512 thr = 4 each)
  {
    const float4* src = (const float4*)(wxg + HH);
    float4* dst = (float4*)wxb;
#pragma unroll
    for (int i = 0; i < 4; ++i) dst[i * 512 + tid] = src[i * 512 + tid];
  }
  // h0[0] = G0(0, wx[0]); h1[-1] = 0
  float hp0, hp1 = 0.f;
  {
    float h00 = gate(wxg[c], 0.f, ebg0, ebu0, sz0, sn0, gc0, kc0);
    hp0 = h00;
    if (g == 0) {
      Hpk[0][0][widx] = (_Float16)h00;
      Hpk[0][1][widx] = (_Float16)0.f;
    }
  }
  asm volatile("s_waitcnt lgkmcnt(0)" ::: "memory");
  __builtin_amdgcn_s_barrier();

  const f32x4 zero = {0.f, 0.f, 0.f, 0.f};

  // persistent A-fragments: zero on n!=0 lanes forever (their D-rows unused)
  half8 a0[4], a1[4];
#pragma unroll
  for (int kt = 0; kt < 4; ++kt) {
    a0[kt] = (half8)(_Float16)0.f;
    a1[kt] = (half8)(_Float16)0.f;
  }

  for (int t = 0; t < SS; ++t) {
    const int rd = t & 1, wb = rd ^ 1;
    const int q = t & (CH - 1);

    // ---- A-fragments: only lanes n==0 carry row 0 (64 B/instr delivered)
    if (n == 0) {
#pragma unroll
      for (int kt = 0; kt < 4; ++kt) {
        a0[kt] = __builtin_bit_cast(half8,
                   *(const uint4*)&Hpk[rd][0][kt * 32 + rbase]);
        a1[kt] = __builtin_bit_cast(half8,
                   *(const uint4*)&Hpk[rd][1][kt * 32 + rbase]);
      }
    }
    float wxv = wxb[q * HH + c];

    // ---- 3 matvec chains for tile w, K chained through the C operand
    f32x4 accA, accB, accC;
#pragma unroll
    for (int kt = 0; kt < 4; ++kt) {
      accA = __builtin_amdgcn_mfma_f32_16x16x32_f16(a0[kt], wfA[kt], kt ? accA : zero, 0, 0, 0);
      accB = __builtin_amdgcn_mfma_f32_16x16x32_f16(a0[kt], wfB[kt], kt ? accB : zero, 0, 0, 0);
      accC = __builtin_amdgcn_mfma_f32_16x16x32_f16(a1[kt], wfC[kt], kt ? accC : zero, 0, 0, 0);
    }

    // ---- gates: valid only on g==0 lanes (D-row 0); g0 does ALL writes
    float pre0 = accA[0] + wxv;
    float hc0 = gate(pre0, hp0, ebg0, ebu0, sz0, sn0, gc0, kc0);
    hp0 = hc0;
    if (g == 0) Hpk[wb][0][widx] = (_Float16)hc0;   // issues before accC done

    float pre1 = accB[0] + accC[0];
    float hc1 = gate(pre1, hp1, ebg1, ebu1, sz1, sn1, gc1, kc1);
    hp1 = hc1;
    if (g == 0) {
      Hpk[wb][1][widx] = (_Float16)hc1;
      outg[(size_t)t * HH + c] = hc1;
      if (t == SS - 2) hn[b * HH + c] = hc0;                 // h0[SS-1]
      if (t == SS - 1) hn[BB * HH + b * HH + c] = hc1;       // h1[SS-1]
    }

    asm volatile("s_waitcnt lgkmcnt(0)" ::: "memory");
    __builtin_amdgcn_s_barrier();

    // ---- chunk boundary: restage wx rows t+2 .. t+65 (clamped)
    if (q == CH - 1 && t + 1 < SS) {
      float4* wdst = (float4*)wxb;
#pragma unroll
      for (int i = 0; i < 4; ++i) {
        int flat4 = i * 512 + tid;
        int row = t + 2 + (flat4 >> 5);
        row = row < SS ? row : SS - 1;
        int col4 = flat4 & 31;
        wdst[flat4] = *(const float4*)(wxg + (size_t)row * HH + col4 * 4);
      }
      asm volatile("s_waitcnt lgkmcnt(0)" ::: "memory");
      __builtin_amdgcn_s_barrier();
    }
  }
}

extern "C" void kernel_launch(void* const* d_in, const int* in_sizes, int n_in,
                              void* d_out, int out_size, void* d_ws, size_t ws_size,
                              hipStream_t stream) {
  const float* x      = (const float*)d_in[0];
  const float* w0     = (const float*)d_in[1];
  const float* u0     = (const float*)d_in[2];
  const float* bg0    = (const float*)d_in[3];
  const float* bu0    = (const float*)d_in[4];
  const float* zeta0  = (const float*)d_in[5];
  const float* nu0    = (const float*)d_in[6];
  const float* lambd0 = (const float*)d_in[7];
  const float* gamma0 = (const float*)d_in[8];
  const float* w1     = (const float*)d_in[9];
  const float* u1     = (const float*)d_in[10];
  const float* bg1    = (const float*)d_in[11];
  const float* bu1    = (const float*)d_in[12];
  const float* zeta1  = (const float*)d_in[13];
  const float* nu1    = (const float*)d_in[14];
  const float* lambd1 = (const float*)d_in[15];
  const float* gamma1 = (const float*)d_in[16];

  float* out = (float*)d_out;                     // out1: [B,S,H]
  float* hn  = out + (size_t)BB * SS * HH;        // h_n:  [2,B,H]
  float* wx0 = (float*)d_ws;                      // scratch: [B,S,H] fp32 (64 MB)

  wx0_kernel<<<(BB * SS) / 32, 256, 0, stream>>>(x, w0, wx0);
  scan_kernel<<<BB, 512, 0, stream>>>(wx0, u0, bg0, bu0, zeta0, nu0, lambd0,
                                      gamma0, w1, u1, bg1, bu1, zeta1, nu1,
                                      lambd1, gamma1, out, hn);
}